// Round 2
// baseline (2254.834 us; speedup 1.0000x reference)
//
#include <hip/hip_runtime.h>
#include <cmath>

#define NLVL 16

struct LevelCfg { float scale; unsigned offset; unsigned res; unsigned hashed; };
struct Cfg { LevelCfg lv[NLVL]; unsigned hm_mask; };

__global__ __launch_bounds__(256) void hashenc_kernel(
    const float* __restrict__ x,
    const float2* __restrict__ grid,
    float2* __restrict__ out,
    Cfg cfg)
{
  __shared__ float s_x[48];
  __shared__ LevelCfg s_cfg[NLVL];
  const unsigned tid = threadIdx.x;
  const unsigned pt0 = blockIdx.x * 16u;           // 16 points per block
  if (tid < NLVL) s_cfg[tid] = cfg.lv[tid];
  if (tid < 48u)  s_x[tid] = x[pt0 * 3u + tid];
  __syncthreads();

  const unsigned lvl = tid & 15u;                  // level per lane
  const unsigned lp  = tid >> 4;                   // local point 0..15
  const LevelCfg c = s_cfg[lvl];

  const float px = s_x[lp * 3 + 0];
  const float py = s_x[lp * 3 + 1];
  const float pz = s_x[lp * 3 + 2];

  // pos = scale*x + 0.5 ; frac = pos - floor(pos) — no FMA contraction,
  // matches the reference's f32 op sequence.
  const float p0 = __fadd_rn(__fmul_rn(c.scale, px), 0.5f);
  const float p1 = __fadd_rn(__fmul_rn(c.scale, py), 0.5f);
  const float p2 = __fadd_rn(__fmul_rn(c.scale, pz), 0.5f);
  const float fl0 = floorf(p0), fl1 = floorf(p1), fl2 = floorf(p2);
  const float fr0 = __fsub_rn(p0, fl0);
  const float fr1 = __fsub_rn(p1, fl1);
  const float fr2 = __fsub_rn(p2, fl2);
  const unsigned b0 = (unsigned)fl0, b1 = (unsigned)fl1, b2 = (unsigned)fl2;

  // hashed-index building blocks (prime for dim0 is 1)
  const unsigned P1 = 2654435761u, P2 = 805459861u;
  const unsigned hx[2] = { b0, b0 + 1u };
  const unsigned hy[2] = { b1 * P1, b1 * P1 + P1 };
  const unsigned hz[2] = { b2 * P2, b2 * P2 + P2 };
  // dense-index building blocks
  const unsigned r = c.res, r2 = r * r;
  const unsigned dbase = b0 + b1 * r + b2 * r2;
  const unsigned dy[2] = { 0u, r };
  const unsigned dz[2] = { 0u, r2 };
  const bool hashed = (c.hashed != 0u);
  const unsigned m = cfg.hm_mask;

  // trilinear weights, product order ((wx*wy)*wz) like jnp.prod
  const float wxv[2] = { __fsub_rn(1.0f, fr0), fr0 };
  const float wyv[2] = { __fsub_rn(1.0f, fr1), fr1 };
  const float wzv[2] = { __fsub_rn(1.0f, fr2), fr2 };

  unsigned idx[8];
  float w[8];
#pragma unroll
  for (int cc = 0; cc < 8; ++cc) {
    const int bx = (cc >> 2) & 1;                  // dim0 (slowest, like itertools.product)
    const int by = (cc >> 1) & 1;                  // dim1
    const int bz = cc & 1;                         // dim2 (fastest)
    const unsigned ih = (hx[bx] ^ hy[by] ^ hz[bz]) & m;
    const unsigned id = dbase + (unsigned)bx + dy[by] + dz[bz];
    idx[cc] = hashed ? ih : id;                    // branchless select (cndmask)
    w[cc] = __fmul_rn(__fmul_rn(wxv[bx], wyv[by]), wzv[bz]);
  }

  const float2* __restrict__ g = grid + c.offset;
  float accx = 0.0f, accy = 0.0f;
#pragma unroll
  for (int cc = 0; cc < 8; ++cc) {                 // 8 independent gathers -> MLP
    const float2 v = g[idx[cc]];
    accx = __fmaf_rn(v.x, w[cc], accx);
    accy = __fmaf_rn(v.y, w[cc], accy);
  }

  // out[point][lvl] as float2 -> index = point*16 + lvl = blockIdx*256 + tid
  out[pt0 * 16u + tid] = make_float2(accx, accy);
}

extern "C" void kernel_launch(void* const* d_in, const int* in_sizes, int n_in,
                              void* d_out, int out_size, void* d_ws, size_t ws_size,
                              hipStream_t stream) {
  const float*  x    = (const float*)d_in[0];
  const float2* grid = (const float2*)d_in[1];
  float2*       out  = (float2*)d_out;

  // Mirror reference _level_config() in double precision (same libm calls
  // CPython's math module makes -> bit-identical scales/res/offsets).
  Cfg cfg;
  const unsigned hashmap_size = 1u << 19;
  const double per_level_scale = exp(log(2048.0 * 1.0 / 16.0) / (NLVL - 1));
  const double b = log2(per_level_scale);
  unsigned n_params = 0;
  for (int i = 0; i < NLVL; ++i) {
    const double scale = pow(2.0, (double)i * b) * 16.0 - 1.0;
    const int res = (int)ceil(scale) + 1;
    const double res3 = pow((double)res, 3.0);
    unsigned p = (unsigned)(ceil(res3 / 8.0) * 8.0);
    if (p > hashmap_size) p = hashmap_size;
    cfg.lv[i].hashed = (res3 > (double)p) ? 1u : 0u;
    cfg.lv[i].offset = n_params;
    cfg.lv[i].scale  = (float)scale;
    cfg.lv[i].res    = (unsigned)res;
    n_params += p;
  }
  cfg.hm_mask = hashmap_size - 1u;

  const unsigned n_points = (unsigned)(in_sizes[0] / 3);
  const unsigned total = n_points * 16u;           // one thread per (point, level)
  hashenc_kernel<<<total / 256u, 256, 0, stream>>>(x, grid, out, cfg);
}